// Round 2
// baseline (115.593 us; speedup 1.0000x reference)
//
#include <hip/hip_runtime.h>
#include <stdint.h>

// Fused Swin window attention for MI355X (gfx950) — R2 "all-transposed" scheme.
// B=4096 windows, N=64 tokens, C=128, H=4 heads, D=32.
// One block = one window; 4 waves = 4 heads; bf16 MFMA 16x16x32, f32 accum.
//
// All GEMMs computed transposed so the MFMA C/D layout (row=lq*4+j, col=l15)
// has its packing direction (j) along the contiguous LDS axis:
//   Q^T/K^T = Wqk^T · x^T   (A = packed W frag, B = x row-read)
//   V       = x · Wv        (A = x row-read,    B = packed W frag)
//   S^T     = K · Q^T       (both operands straight from LDS row-reads)
//   O^T     = V^T · P^T     (A = Vt row-read,   B = P row-read)
//   OUT^T   = Wp^T · O^T    (A = packed W frag, B = O row-read)
// => every LDS write is a cvt_pk'd b32/b64; final store is direct float4.
//
// LDS (48 KB -> 3 blocks/CU):
//   region A [0,16K):   x bf16 [64 tok][256B] swz  ->  Vt [4 heads][32 d][128B] swz
//                       ->  O bf16 [64 tok][256B] swz
//   region B [16K,48K): per-head [64 tok][128B]: Q bytes 0..63 | K bytes 64..127;
//                       aliased by P [64 q][128B key] after QK frags are in regs.
// d_ws: wq bf16 @0 (96KB) | wp bf16 @98304 (32KB) | bias_full f32 [H][64][64] @131072

typedef __attribute__((ext_vector_type(4))) float  f32x4;
typedef __attribute__((ext_vector_type(8))) __bf16 bf16x8;

#define DEV static __device__ __forceinline__

DEV unsigned short f2bf(float f) {          // f32 -> bf16 RNE (prep kernel only)
  unsigned int u = __float_as_uint(f);
  u += 0x7FFFu + ((u >> 16) & 1u);
  return (unsigned short)(u >> 16);
}

DEV unsigned int pk2(float a, float b) {    // packed bf16x2 via compiler casts
  __bf16 x = (__bf16)a, y = (__bf16)b;
  unsigned short ux = __builtin_bit_cast(unsigned short, x);
  unsigned short uy = __builtin_bit_cast(unsigned short, y);
  return (unsigned int)ux | ((unsigned int)uy << 16);
}

// Swizzled LDS byte addresses (XOR multiples of 16 keep 4/8/16B alignment;
// bits 0-3 untouched). Writer/reader share the function -> layout-independent.
DEV int xaddr (int r, int cb) { return r*256 + (cb ^ ((r & 7) << 4)); }  // 256B rows (x / O)
DEV int qkaddr(int r, int cb) { return r*128 + (cb ^ ((r & 7) << 4)); }  // 128B rows (Q|K, P)
DEV int vtaddr(int d, int cb) { return d*128 + (cb ^ ((d & 7) << 4)); }  // 128B rows (Vt)

DEV f32x4 mfma16(bf16x8 a, bf16x8 b, f32x4 c) {
  return __builtin_amdgcn_mfma_f32_16x16x32_bf16(a, b, c, 0, 0, 0);
}

// Pack weights into the shared A/B fragment order and expand rel-pos bias.
// Frag: lane l holds W[k=ks*32+(l>>4)*8+i][col=nt*16+(l&15)], i=0..7 (16B/lane).
// This single pack serves as B-frag of W and as A-frag of W^T (identical data).
__global__ void prep_kernel(const float* __restrict__ qkv_w, const float* __restrict__ proj_w,
                            const float* __restrict__ bias_table,
                            unsigned short* __restrict__ wq, unsigned short* __restrict__ wp,
                            float* __restrict__ bias_full) {
  int idx = blockIdx.x * 256 + threadIdx.x;
  if (idx < 49152) {                                    // qkv_w (128 x 384)
    int i = idx & 7, lane = (idx >> 3) & 63, ks = (idx >> 9) & 3, nt = idx >> 11;
    int k = ks*32 + (lane >> 4)*8 + i;
    int col = nt*16 + (lane & 15);
    wq[idx] = f2bf(qkv_w[k*384 + col]);
  } else if (idx < 65536) {                             // proj_w (128 x 128)
    int t = idx - 49152;
    int i = t & 7, lane = (t >> 3) & 63, ks = (t >> 9) & 3, nt = t >> 11;
    int k = ks*32 + (lane >> 4)*8 + i;
    int col = nt*16 + (lane & 15);
    wp[t] = f2bf(proj_w[k*128 + col]);
  } else if (idx < 81920) {                             // bias_full[h][q][k]
    int t = idx - 65536;
    int h = t >> 12, q = (t >> 6) & 63, kk = t & 63;
    int ri = q >> 3, ci = q & 7, rj = kk >> 3, cj = kk & 7;
    bias_full[t] = bias_table[((ri - rj + 7)*15 + (ci - cj + 7))*4 + h];
  }
}

__global__ __launch_bounds__(256, 3) void fused_kernel(
    const float* __restrict__ x, const float* __restrict__ qkv_b, const float* __restrict__ proj_b,
    const unsigned short* __restrict__ wq, const unsigned short* __restrict__ wp,
    const float* __restrict__ bias_full, float* __restrict__ out)
{
  __shared__ __align__(16) char lds[49152];
  const int b    = blockIdx.x;
  const int tid  = threadIdx.x;
  const int lane = tid & 63;
  const int w    = tid >> 6;       // wave id == head id
  const int l15  = lane & 15;
  const int lq   = lane >> 4;      // quarter-wave 0..3
  const float SCALE = 0.17677669529663687f;   // D^-0.5
  const f32x4 FZ = {0.f, 0.f, 0.f, 0.f};

  // ---------- Phase 0: stage x -> region A as bf16 (swizzled) ----------
  {
    const float4* x4 = (const float4*)(x + (size_t)b * 8192);
    #pragma unroll
    for (int it = 0; it < 8; ++it) {
      int f4 = it*256 + tid;                 // 0..2047
      int r = f4 >> 5, c4 = f4 & 31;
      float4 v = x4[f4];
      *(uint2*)(lds + xaddr(r, c4*8)) = make_uint2(pk2(v.x, v.y), pk2(v.z, v.w));
    }
  }
  __syncthreads();

  // ---------- Phase 1: transposed QKV GEMM (wave = head) ----------
  // qacc/kacc[t][m]: tile (feature t, token m); vacc[m][dt]: tile (token m, d dt)
  f32x4 qacc[2][4], kacc[2][4], vacc[4][2];
  #pragma unroll
  for (int t = 0; t < 2; ++t)
    #pragma unroll
    for (int m = 0; m < 4; ++m) { qacc[t][m] = FZ; kacc[t][m] = FZ; }
  #pragma unroll
  for (int m = 0; m < 4; ++m) { vacc[m][0] = FZ; vacc[m][1] = FZ; }

  #pragma unroll
  for (int ks = 0; ks < 4; ++ks) {
    bf16x8 xfr[4];   // lane: x[tok=m*16+l15][c=ks*32+lq*8+i] — B-frag of x^T AND A-frag of x
    #pragma unroll
    for (int m = 0; m < 4; ++m)
      xfr[m] = *(const bf16x8*)(lds + xaddr(m*16 + l15, ks*64 + lq*16));
    #pragma unroll
    for (int t = 0; t < 2; ++t) {
      bf16x8 wfq = *(const bf16x8*)((const char*)wq + (((2*w + t)*4      + ks)*64 + lane)*16);
      bf16x8 wfk = *(const bf16x8*)((const char*)wq + (((8 + 2*w + t)*4  + ks)*64 + lane)*16);
      bf16x8 wfv = *(const bf16x8*)((const char*)wq + (((16 + 2*w + t)*4 + ks)*64 + lane)*16);
      #pragma unroll
      for (int m = 0; m < 4; ++m) {
        qacc[t][m] = mfma16(wfq, xfr[m], qacc[t][m]);   // Q^T = Wq^T x^T
        kacc[t][m] = mfma16(wfk, xfr[m], kacc[t][m]);   // K^T = Wk^T x^T
        vacc[m][t] = mfma16(xfr[m], wfv, vacc[m][t]);   // V   = x Wv
      }
    }
  }
  __syncthreads();   // all waves done reading x; region A reusable (Vt)

  // ---------- Epilogue: Q|K -> region B (packed b32), V^T -> region A (packed b64) ----------
  char* qkb = lds + 16384 + w*8192;   // [64 tok][128B]: Q @0..63, K @64..127
  char* vtb = lds + w*4096;           // Vt [32 d][128B key]
  #pragma unroll
  for (int t = 0; t < 2; ++t) {
    float4 bq4 = *(const float4*)(qkv_b +        w*32 + t*16 + lq*4);
    float4 bk4 = *(const float4*)(qkv_b + 128 +  w*32 + t*16 + lq*4);
    #pragma unroll
    for (int m = 0; m < 4; ++m) {
      int row = m*16 + l15;                       // token
      int cb  = (t*16 + lq*4)*2;                  // d byte offset
      *(unsigned int*)(qkb + qkaddr(row, cb))
          = pk2((qacc[t][m][0] + bq4.x)*SCALE, (qacc[t][m][1] + bq4.y)*SCALE);
      *(unsigned int*)(qkb + qkaddr(row, cb + 4))
          = pk2((qacc[t][m][2] + bq4.z)*SCALE, (qacc[t][m][3] + bq4.w)*SCALE);
      *(unsigned int*)(qkb + qkaddr(row, 64 + cb))
          = pk2(kacc[t][m][0] + bk4.x, kacc[t][m][1] + bk4.y);
      *(unsigned int*)(qkb + qkaddr(row, 64 + cb + 4))
          = pk2(kacc[t][m][2] + bk4.z, kacc[t][m][3] + bk4.w);
    }
  }
  #pragma unroll
  for (int dt = 0; dt < 2; ++dt) {
    float bv = qkv_b[256 + w*32 + dt*16 + l15];   // per-d bias
    #pragma unroll
    for (int m = 0; m < 4; ++m) {
      // vacc[m][dt]: (tok=m*16+lq*4+j, d=dt*16+l15) -> Vt[d][key]: 4 consecutive keys
      *(uint2*)(vtb + vtaddr(dt*16 + l15, (m*16 + lq*4)*2)) =
        make_uint2(pk2(vacc[m][dt][0] + bv, vacc[m][dt][1] + bv),
                   pk2(vacc[m][dt][2] + bv, vacc[m][dt][3] + bv));
    }
  }

  // ---------- Phase 2: attention (wave-local) ----------
  bf16x8 qf[4], kf[4];
  #pragma unroll
  for (int m = 0; m < 4; ++m) {
    qf[m] = *(const bf16x8*)(qkb + qkaddr(m*16 + l15,      lq*16));  // Q[q=l15][d]
    kf[m] = *(const bf16x8*)(qkb + qkaddr(m*16 + l15, 64 + lq*16));  // K[key=l15][d]
  }
  f32x4 s[4][4];   // S^T tile (key n, q m): row=key=lq*4+j, col=q=l15
  #pragma unroll
  for (int n = 0; n < 4; ++n)
    #pragma unroll
    for (int m = 0; m < 4; ++m)
      s[n][m] = mfma16(kf[n], qf[m], FZ);

  const float* bh = bias_full + w*4096;
  #pragma unroll
  for (int n = 0; n < 4; ++n)
    #pragma unroll
    for (int m = 0; m < 4; ++m) {
      float4 b4 = *(const float4*)(bh + (m*16 + l15)*64 + n*16 + lq*4);
      s[n][m][0] += b4.x; s[n][m][1] += b4.y; s[n][m][2] += b4.z; s[n][m][3] += b4.w;
    }

  // Row softmax over keys (keys live on (n, j, lq) — per-lane 16 + 2 shuffles).
  // P kept unnormalized; 1/sum folded into the O^T rescale.
  float inv_[4];
  #pragma unroll
  for (int m = 0; m < 4; ++m) {
    float mx = s[0][m][0];
    #pragma unroll
    for (int n = 0; n < 4; ++n)
      #pragma unroll
      for (int j = 0; j < 4; ++j) mx = fmaxf(mx, s[n][m][j]);
    mx = fmaxf(mx, __shfl_xor(mx, 16));
    mx = fmaxf(mx, __shfl_xor(mx, 32));
    float sum = 0.f;
    #pragma unroll
    for (int n = 0; n < 4; ++n)
      #pragma unroll
      for (int j = 0; j < 4; ++j) {
        float p = __expf(s[n][m][j] - mx);
        s[n][m][j] = p;
        sum += p;
      }
    sum += __shfl_xor(sum, 16);
    sum += __shfl_xor(sum, 32);
    inv_[m] = __fdividef(1.f, sum);
  }

  // P -> region B (aliases dead Q|K bytes; same wave, program order suffices)
  #pragma unroll
  for (int n = 0; n < 4; ++n)
    #pragma unroll
    for (int m = 0; m < 4; ++m) {
      int row = m*16 + l15;                 // q
      int cb  = (n*16 + lq*4)*2;            // key byte offset
      *(unsigned int*)(qkb + qkaddr(row, cb))     = pk2(s[n][m][0], s[n][m][1]);
      *(unsigned int*)(qkb + qkaddr(row, cb + 4)) = pk2(s[n][m][2], s[n][m][3]);
    }

  // O^T = V^T P^T  (A = Vt row-read, B = P row-read)
  f32x4 o[2][4];   // tile (d dt, q m): row=d=lq*4+j, col=q=l15
  #pragma unroll
  for (int dt = 0; dt < 2; ++dt)
    #pragma unroll
    for (int m = 0; m < 4; ++m) o[dt][m] = FZ;
  #pragma unroll
  for (int ks = 0; ks < 2; ++ks) {
    bf16x8 vf[2], pf[4];
    #pragma unroll
    for (int dt = 0; dt < 2; ++dt)
      vf[dt] = *(const bf16x8*)(vtb + vtaddr(dt*16 + l15, ks*64 + lq*16));
    #pragma unroll
    for (int m = 0; m < 4; ++m)
      pf[m] = *(const bf16x8*)(qkb + qkaddr(m*16 + l15, ks*64 + lq*16));
    #pragma unroll
    for (int dt = 0; dt < 2; ++dt)
      #pragma unroll
      for (int m = 0; m < 4; ++m)
        o[dt][m] = mfma16(vf[dt], pf[m], o[dt][m]);
  }
  __syncthreads();   // Vt dead everywhere -> region A reusable (O)

  // O (normalized, bf16) -> region A [tok][c], packed b32 along d
  #pragma unroll
  for (int dt = 0; dt < 2; ++dt)
    #pragma unroll
    for (int m = 0; m < 4; ++m) {
      int row = m*16 + l15;                          // token
      int cb  = (w*32 + dt*16 + lq*4)*2;             // channel byte offset
      *(unsigned int*)(lds + xaddr(row, cb))
          = pk2(o[dt][m][0]*inv_[m], o[dt][m][1]*inv_[m]);
      *(unsigned int*)(lds + xaddr(row, cb + 4))
          = pk2(o[dt][m][2]*inv_[m], o[dt][m][3]*inv_[m]);
    }
  __syncthreads();   // O complete

  // ---------- Phase 3: OUT^T = Wp^T O^T, direct float4 global stores ----------
  f32x4 pacc[2][4];
  #pragma unroll
  for (int t = 0; t < 2; ++t)
    #pragma unroll
    for (int m = 0; m < 4; ++m) pacc[t][m] = FZ;
  #pragma unroll
  for (int ks = 0; ks < 4; ++ks) {
    bf16x8 ofr[4];
    #pragma unroll
    for (int m = 0; m < 4; ++m)
      ofr[m] = *(const bf16x8*)(lds + xaddr(m*16 + l15, ks*64 + lq*16));
    #pragma unroll
    for (int t = 0; t < 2; ++t) {
      bf16x8 wf = *(const bf16x8*)((const char*)wp + (((2*w + t)*4 + ks)*64 + lane)*16);
      #pragma unroll
      for (int m = 0; m < 4; ++m)
        pacc[t][m] = mfma16(wf, ofr[m], pacc[t][m]);
    }
  }

  float* ob = out + (size_t)b * 8192;
  #pragma unroll
  for (int t = 0; t < 2; ++t) {
    float4 pb4 = *(const float4*)(proj_b + (2*w + t)*16 + lq*4);
    #pragma unroll
    for (int m = 0; m < 4; ++m) {
      float4 v;
      v.x = pacc[t][m][0] + pb4.x;
      v.y = pacc[t][m][1] + pb4.y;
      v.z = pacc[t][m][2] + pb4.z;
      v.w = pacc[t][m][3] + pb4.w;
      // out[tok = m*16+l15][f = (2w+t)*16 + lq*4 + j] — 16 x 64B segments / store
      *(float4*)(ob + (m*16 + l15)*128 + (2*w + t)*16 + lq*4) = v;
    }
  }
}

extern "C" void kernel_launch(void* const* d_in, const int* in_sizes, int n_in,
                              void* d_out, int out_size, void* d_ws, size_t ws_size,
                              hipStream_t stream) {
  const float* x        = (const float*)d_in[0];
  const float* qkv_w    = (const float*)d_in[1];
  const float* qkv_b    = (const float*)d_in[2];
  const float* proj_w   = (const float*)d_in[3];
  const float* proj_b   = (const float*)d_in[4];
  const float* bias_tab = (const float*)d_in[5];
  float* out = (float*)d_out;

  unsigned short* wq = (unsigned short*)d_ws;                      // 96 KB
  unsigned short* wp = (unsigned short*)((char*)d_ws + 98304);     // 32 KB
  float* bias_full   = (float*)((char*)d_ws + 131072);             // 64 KB

  int B = in_sizes[0] / 8192;   // (B, 64, 128)

  prep_kernel<<<320, 256, 0, stream>>>(qkv_w, proj_w, bias_tab, wq, wp, bias_full);
  fused_kernel<<<B, 256, 0, stream>>>(x, qkv_b, proj_b, wq, wp, bias_full, out);
}